// Round 5
// baseline (4268713.672 us; speedup 1.0000x reference)
//
#include <hip/hip_runtime.h>
#include <hip/hip_fp16.h>

#define H_ 1024
#define B_ 256
#define T_ 256
#define C_ 10
#define MAGIC_ 0x5EED5EEDu

typedef _Float16 f16x8 __attribute__((ext_vector_type(8)));
typedef float f32x4 __attribute__((ext_vector_type(4)));

__device__ __forceinline__ float sigm_f(float v) { return 1.f / (1.f + __expf(-v)); }
__device__ __forceinline__ float tanh_f(float v) {
  v = fminf(fmaxf(v, -15.f), 15.f);
  float e = __expf(2.f * v);
  return (e - 1.f) / (e + 1.f);
}

// proven slow path (cross-XCD safe): coherence-point load, bypasses L1+L2
__device__ __forceinline__ f16x8 load_h8_agent(const _Float16* p) {
  const unsigned long long* q = reinterpret_cast<const unsigned long long*>(p);
  unsigned long long lo = __hip_atomic_load(q,     __ATOMIC_RELAXED, __HIP_MEMORY_SCOPE_AGENT);
  unsigned long long hi = __hip_atomic_load(q + 1, __ATOMIC_RELAXED, __HIP_MEMORY_SCOPE_AGENT);
  union { unsigned long long u[2]; f16x8 v; } r;
  r.u[0] = lo; r.u[1] = hi;
  return r.v;
}

// fast path: L1-bypass, L2-served (same-XCD visible) loads/stores
__device__ __forceinline__ unsigned load_sc0(const unsigned int* p) {
  unsigned v;
  asm volatile("global_load_dword %0, %1, off sc0\n\ts_waitcnt vmcnt(0)"
               : "=v"(v) : "v"(p) : "memory");
  return v;
}
__device__ __forceinline__ void store_sc0(unsigned int* p, unsigned v) {
  asm volatile("global_store_dword %0, %1, off sc0" :: "v"(p), "v"(v) : "memory");
}
// 16B sc0 load, issue-only — caller does one s_waitcnt vmcnt(0) for the batch
#define GL16_SC0(dst, base, byteoff) \
  asm volatile("global_load_dwordx4 %0, %1, off offset:" #byteoff " sc0" \
               : "=v"(dst) : "v"(base))

// Persistent LSTM. Grid: 256 WGs = 32 row-groups (r) x 8 col-groups (g).
// Each WG: 32 hidden units x 32 batch cols, all 4 gates; weights stationary in
// registers (row permutation m = 4*u + gate). h(t) exchange between the 32 WGs
// of a col-group:
//   FAST: sc0 stores -> XCD L2; sc0 loads (L1-bypass) <- L2. Verified at
//         runtime by an end-to-end probe of this exact mechanism; any WG that
//         fails the probe vetoes (agent-scope vote) and the whole group runs:
//   SLOW: agent-scope atomics through the coherence point (r2-proven).
// Both modes execute identical FP ops in identical order -> identical bits.
__global__ __launch_bounds__(512, 2) void lstm_main(
    const float* __restrict__ x,
    const float* __restrict__ Wgh, const float* __restrict__ Wih,
    const float* __restrict__ Wfh, const float* __restrict__ Woh,
    const float* __restrict__ Wgx, const float* __restrict__ Wix,
    const float* __restrict__ Wfx, const float* __restrict__ Wox,
    const float* __restrict__ bg, const float* __restrict__ bi,
    const float* __restrict__ bf, const float* __restrict__ bo,
    _Float16* __restrict__ hT, unsigned int* __restrict__ flags,
    unsigned int* __restrict__ probe, unsigned int* __restrict__ scal)
{
  const int bid  = blockIdx.x;
  const int g    = bid & 7;      // col group
  const int r    = bid >> 3;     // row group 0..31
  const int tid  = threadIdx.x;
  const int wid  = tid >> 6;     // wave 0..7
  const int lane = tid & 63;
  const int mg   = wid >> 2;     // M-group 0..1
  const int kg   = wid & 3;      // K-slice 0..3
  const int q    = lane >> 4;    // 0..3
  const int rlo  = lane & 15;
  const int c0   = g * 32;       // batch col base

  __shared__ float part[32 * 4 * 128];  // [c_local][kg][m] f32, XOR-swizzled
  __shared__ unsigned mode_sh;

  // ---- probe phase 1: publish my slot via the fast-path store mechanism ----
  if (tid == 0) {
    store_sc0(probe + (size_t)(g * 32 + r) * 16, MAGIC_);
    asm volatile("s_waitcnt vmcnt(0)" ::: "memory");
  }

  // ---- A fragments: stationary weights in registers (overlaps probe) ------
  f16x8 A[32];
  {
    const int gate = rlo & 3;
    const float* Wsel = (gate == 0) ? Wgh : (gate == 1) ? Wih : (gate == 2) ? Wfh : Woh;
    #pragma unroll
    for (int f = 0; f < 32; ++f) {
      const int mt  = f >> 3, kkl = f & 7;
      const int u   = mg * 16 + mt * 4 + (rlo >> 2);
      const int k   = kg * 256 + kkl * 32 + q * 8;
      const float4* p = reinterpret_cast<const float4*>(
          Wsel + (size_t)(r * 32 + u) * H_ + k);
      float4 lo = p[0], hi = p[1];
      f16x8 a;
      a[0]=(_Float16)lo.x; a[1]=(_Float16)lo.y; a[2]=(_Float16)lo.z; a[3]=(_Float16)lo.w;
      a[4]=(_Float16)hi.x; a[5]=(_Float16)hi.y; a[6]=(_Float16)hi.z; a[7]=(_Float16)hi.w;
      A[f] = a;
    }
  }

  // ---- probe phase 2: can this WG see all 32 group slots via sc0 loads? ---
  if (wid == 0) {
    unsigned ok = 0;
    int guard = 0;
    for (;;) {
      unsigned v = MAGIC_;
      if (lane < 32) v = load_sc0(probe + (size_t)(g * 32 + lane) * 16);
      if (__all((int)(v == MAGIC_))) { ok = 1; break; }
      if (++guard > (1 << 18)) { ok = 0; break; }
      __builtin_amdgcn_s_sleep(2);
    }
    if (tid == 0) {
      unsigned* fail   = scal + g;
      unsigned* ready2 = scal + 8 + g;
      if (!ok)
        __hip_atomic_fetch_or(fail, 1u, __ATOMIC_RELAXED, __HIP_MEMORY_SCOPE_AGENT);
      __hip_atomic_fetch_add(ready2, 1u, __ATOMIC_RELEASE, __HIP_MEMORY_SCOPE_AGENT);
      int g2 = 0; bool trip = false;
      while (__hip_atomic_load(ready2, __ATOMIC_RELAXED, __HIP_MEMORY_SCOPE_AGENT) < 32u) {
        if (++g2 > (1 << 20)) { trip = true; break; }
        __builtin_amdgcn_s_sleep(2);
      }
      unsigned f = __hip_atomic_load(fail, __ATOMIC_ACQUIRE, __HIP_MEMORY_SCOPE_AGENT);
      mode_sh = (f == 0u && !trip) ? 1u : 2u;   // unanimous fast, else slow
    }
  }
  __syncthreads();
  const bool fast = (mode_sh == 1u);

  // ---- per-thread elementwise constants -----------------------------------
  const int c_l = tid >> 4;
  const int uu  = tid & 15;
  float wx0[4], wx1[4], bb0[4], bb1[4];
  {
    const int u0 = r * 32 + uu, u1 = u0 + 16;
    wx0[0]=Wgx[u0]; wx0[1]=Wix[u0]; wx0[2]=Wfx[u0]; wx0[3]=Wox[u0];
    wx1[0]=Wgx[u1]; wx1[1]=Wix[u1]; wx1[2]=Wfx[u1]; wx1[3]=Wox[u1];
    bb0[0]=bg[u0];  bb0[1]=bi[u0];  bb0[2]=bf[u0];  bb0[3]=bo[u0];
    bb1[0]=bg[u1];  bb1[1]=bi[u1];  bb1[2]=bf[u1];  bb1[3]=bo[u1];
  }
  float cs0 = 0.f, cs1 = 0.f;
  const float* xrow = x + (size_t)(c0 + c_l) * T_;

  unsigned int* myflags = flags + ((size_t)(g * 32 + kg * 8 + (lane & 7)) * 16);
  unsigned int* ownflag = flags + ((size_t)(g * 32 + r) * 16);

  for (int t = 0; t < T_; ++t) {
    const float xv = xrow[t];

    // ---- per-wave wait: only the 8 producers feeding this K-slice ----
    if (t > 0) {
      const unsigned tgt = (unsigned)t;
      int guard = 0;
      if (fast) {
        for (;;) {
          unsigned v = tgt;
          if (lane < 8) v = load_sc0(myflags);
          if (__all((int)(v >= tgt))) break;
          if (++guard > (1 << 17)) break;  // fail fast (absmax), never grind
          __builtin_amdgcn_s_sleep(1);
        }
      } else {
        for (;;) {
          unsigned v = tgt;
          if (lane < 8)
            v = __hip_atomic_load(myflags, __ATOMIC_RELAXED, __HIP_MEMORY_SCOPE_AGENT);
          if (__all((int)(v >= tgt))) break;
          if (++guard > (1 << 20)) break;
          __builtin_amdgcn_s_sleep(1);
        }
      }
      asm volatile("" ::: "memory");
    }

    // ---- GEMM: preactivations for this WG's 128(M) x 32(N) tile ----
    const _Float16* hbuf = hT + (size_t)(t & 1) * (B_ * H_);
    const _Float16* hb0 = hbuf + (size_t)(c0 + rlo) * H_ + kg * 256 + q * 8;
    const _Float16* hb1 = hb0 + 16 * (size_t)H_;

    f32x4 acc[4][2];
    #pragma unroll
    for (int mt = 0; mt < 4; ++mt) {
      acc[mt][0] = (f32x4){0.f, 0.f, 0.f, 0.f};
      acc[mt][1] = (f32x4){0.f, 0.f, 0.f, 0.f};
    }

    if (fast) {
      // issue all 16 sc0 B-fragment loads, one wait, then pure MFMA
      f16x8 B0[8], B1[8];
      GL16_SC0(B0[0], hb0, 0);   GL16_SC0(B1[0], hb1, 0);
      GL16_SC0(B0[1], hb0, 64);  GL16_SC0(B1[1], hb1, 64);
      GL16_SC0(B0[2], hb0, 128); GL16_SC0(B1[2], hb1, 128);
      GL16_SC0(B0[3], hb0, 192); GL16_SC0(B1[3], hb1, 192);
      GL16_SC0(B0[4], hb0, 256); GL16_SC0(B1[4], hb1, 256);
      GL16_SC0(B0[5], hb0, 320); GL16_SC0(B1[5], hb1, 320);
      GL16_SC0(B0[6], hb0, 384); GL16_SC0(B1[6], hb1, 384);
      GL16_SC0(B0[7], hb0, 448); GL16_SC0(B1[7], hb1, 448);
      asm volatile("s_waitcnt vmcnt(0)" ::: "memory");
      __builtin_amdgcn_sched_barrier(0);   // rule #18: pin MFMA after the wait
      #pragma unroll
      for (int kkl = 0; kkl < 8; ++kkl) {
        #pragma unroll
        for (int mt = 0; mt < 4; ++mt) {
          acc[mt][0] = __builtin_amdgcn_mfma_f32_16x16x32_f16(A[mt*8+kkl], B0[kkl], acc[mt][0], 0, 0, 0);
          acc[mt][1] = __builtin_amdgcn_mfma_f32_16x16x32_f16(A[mt*8+kkl], B1[kkl], acc[mt][1], 0, 0, 0);
        }
      }
    } else {
      #pragma unroll
      for (int kkl = 0; kkl < 8; ++kkl) {
        f16x8 b0 = load_h8_agent(hb0 + kkl * 32);
        f16x8 b1 = load_h8_agent(hb1 + kkl * 32);
        #pragma unroll
        for (int mt = 0; mt < 4; ++mt) {
          acc[mt][0] = __builtin_amdgcn_mfma_f32_16x16x32_f16(A[mt*8+kkl], b0, acc[mt][0], 0, 0, 0);
          acc[mt][1] = __builtin_amdgcn_mfma_f32_16x16x32_f16(A[mt*8+kkl], b1, acc[mt][1], 0, 0, 0);
        }
      }
    }

    // ---- K-partials to LDS (C/D layout: col=lane&15, row=(lane>>4)*4+reg) ----
    #pragma unroll
    for (int mt = 0; mt < 4; ++mt) {
      #pragma unroll
      for (int nt = 0; nt < 2; ++nt) {
        const int c_loc = nt * 16 + rlo;
        const int m = mg * 64 + mt * 16 + 4 * q;
        unsigned addr = (unsigned)(c_loc * 2048 + kg * 512 + m * 4);
        addr ^= (unsigned)((c_loc & 7) << 4);
        *reinterpret_cast<f32x4*>(reinterpret_cast<char*>(part) + addr) = acc[mt][nt];
      }
    }
    __syncthreads();

    // ---- reduce over kg + gate nonlinearities + state update ----
    unsigned short hbits0, hbits1;
    {
      unsigned lin = (unsigned)(c_l * 2048 + uu * 16);
      f32x4 s = *reinterpret_cast<const f32x4*>(
          reinterpret_cast<const char*>(part) + (lin ^ ((unsigned)(c_l & 7) << 4)));
      #pragma unroll
      for (int kgi = 1; kgi < 4; ++kgi) {
        unsigned l2 = lin + (unsigned)(kgi * 512);
        s += *reinterpret_cast<const f32x4*>(
            reinterpret_cast<const char*>(part) + (l2 ^ ((unsigned)(c_l & 7) << 4)));
      }
      float pg = s[0] + wx0[0]*xv + bb0[0];
      float pi = s[1] + wx0[1]*xv + bb0[1];
      float pf = s[2] + wx0[2]*xv + bb0[2];
      float po = s[3] + wx0[3]*xv + bb0[3];
      float gg = tanh_f(pg), ii = sigm_f(pi), ff = sigm_f(pf), oo = sigm_f(po);
      cs0 = gg * ii + cs0 * ff;
      hbits0 = __builtin_bit_cast(unsigned short, (_Float16)(tanh_f(cs0) * oo));
    }
    {
      unsigned lin = (unsigned)(c_l * 2048 + (uu + 16) * 16);
      f32x4 s = *reinterpret_cast<const f32x4*>(
          reinterpret_cast<const char*>(part) + (lin ^ ((unsigned)(c_l & 7) << 4)));
      #pragma unroll
      for (int kgi = 1; kgi < 4; ++kgi) {
        unsigned l2 = lin + (unsigned)(kgi * 512);
        s += *reinterpret_cast<const f32x4*>(
            reinterpret_cast<const char*>(part) + (l2 ^ ((unsigned)(c_l & 7) << 4)));
      }
      float pg = s[0] + wx1[0]*xv + bb1[0];
      float pi = s[1] + wx1[1]*xv + bb1[1];
      float pf = s[2] + wx1[2]*xv + bb1[2];
      float po = s[3] + wx1[3]*xv + bb1[3];
      float gg = tanh_f(pg), ii = sigm_f(pi), ff = sigm_f(pf), oo = sigm_f(po);
      cs1 = gg * ii + cs1 * ff;
      hbits1 = __builtin_bit_cast(unsigned short, (_Float16)(tanh_f(cs1) * oo));
    }

    // ---- store h(t+1) to the other parity buffer ----
    {
      _Float16* hout = hT + (size_t)((t + 1) & 1) * (B_ * H_)
                          + (size_t)(c0 + c_l) * H_ + r * 32;
      int nb0 = __shfl_down((int)hbits0, 1);
      int nb1 = __shfl_down((int)hbits1, 1);
      if ((uu & 1) == 0) {
        unsigned v0 = (unsigned)hbits0 | ((unsigned)(unsigned short)nb0 << 16);
        unsigned v1 = (unsigned)hbits1 | ((unsigned)(unsigned short)nb1 << 16);
        unsigned int* p0 = reinterpret_cast<unsigned int*>(hout + uu);
        unsigned int* p1 = reinterpret_cast<unsigned int*>(hout + uu + 16);
        if (fast && t != T_ - 1) {
          store_sc0(p0, v0);          // visible at XCD L2
          store_sc0(p1, v1);
        } else {
          // slow mode, and the final step in BOTH modes (lstm_proj runs on a
          // fresh kernel on arbitrary XCDs -> h(T) must be at the IC)
          __hip_atomic_store(p0, v0, __ATOMIC_RELAXED, __HIP_MEMORY_SCOPE_AGENT);
          __hip_atomic_store(p1, v1, __ATOMIC_RELAXED, __HIP_MEMORY_SCOPE_AGENT);
        }
      }
    }
    // per-thread drain: inline-asm stores are NOT tracked by __syncthreads
    asm volatile("s_waitcnt vmcnt(0)" ::: "memory");
    __syncthreads();   // now every thread's h stores are L2/IC-acked
    if (tid == 0) {
      if (fast) {
        store_sc0(ownflag, (unsigned)(t + 1));
      } else {
        __hip_atomic_store(ownflag, (unsigned)(t + 1),
                           __ATOMIC_RELAXED, __HIP_MEMORY_SCOPE_AGENT);
      }
    }
  }
}

// out[b][cls] = sum_u W_ph[cls][u] * h_final[u][b] + b_p[cls]
__global__ void lstm_proj(const _Float16* __restrict__ hT,
                          const float* __restrict__ Wph,
                          const float* __restrict__ bp,
                          float* __restrict__ out)
{
  const int b = blockIdx.x;
  const int l = threadIdx.x;
  const _Float16* hrow = hT + (size_t)b * H_;  // T even -> final h in parity-0
  float p[C_];
  #pragma unroll
  for (int cls = 0; cls < C_; ++cls) p[cls] = 0.f;
  for (int u = l; u < H_; u += 64) {
    float hv = (float)hrow[u];
    #pragma unroll
    for (int cls = 0; cls < C_; ++cls) p[cls] += hv * Wph[cls * H_ + u];
  }
  #pragma unroll
  for (int cls = 0; cls < C_; ++cls) {
    float v = p[cls];
    #pragma unroll
    for (int off = 32; off > 0; off >>= 1) v += __shfl_down(v, off);
    if (l == 0) out[b * C_ + cls] = v + bp[cls];
  }
}

extern "C" void kernel_launch(void* const* d_in, const int* in_sizes, int n_in,
                              void* d_out, int out_size, void* d_ws, size_t ws_size,
                              hipStream_t stream) {
  const float* x   = (const float*)d_in[0];
  const float* Wgx = (const float*)d_in[1];
  const float* Wgh = (const float*)d_in[2];
  const float* Wix = (const float*)d_in[3];
  const float* Wih = (const float*)d_in[4];
  const float* Wfx = (const float*)d_in[5];
  const float* Wfh = (const float*)d_in[6];
  const float* Wox = (const float*)d_in[7];
  const float* Woh = (const float*)d_in[8];
  const float* Wph = (const float*)d_in[9];
  const float* bg  = (const float*)d_in[10];
  const float* bi  = (const float*)d_in[11];
  const float* bf  = (const float*)d_in[12];
  const float* bo  = (const float*)d_in[13];
  const float* bp  = (const float*)d_in[14];
  float* out = (float*)d_out;

  // ws layout: [0,1MB) hT fp16 double buffer [2][B][H];
  //            [1MB,+16KB)  per-producer flags (256 x 64B)
  //            [+16KB,+16KB) probe slots (256 x 64B)
  //            [+32KB,+4KB)  vote scalars (fail[8], ready2[8])
  _Float16* hT = (_Float16*)d_ws;
  const size_t hT_bytes = (size_t)2 * B_ * H_ * sizeof(_Float16);  // 1 MiB
  unsigned int* flags = (unsigned int*)((char*)d_ws + hT_bytes);
  unsigned int* probe = (unsigned int*)((char*)d_ws + hT_bytes + 16384);
  unsigned int* scal  = (unsigned int*)((char*)d_ws + hT_bytes + 32768);

  hipMemsetAsync(d_ws, 0, hT_bytes + 32768 + 4096, stream);

  lstm_main<<<256, 512, 0, stream>>>(x, Wgh, Wih, Wfh, Woh,
                                     Wgx, Wix, Wfx, Wox,
                                     bg, bi, bf, bo, hT, flags, probe, scal);
  lstm_proj<<<256, 64, 0, stream>>>(hT, Wph, bp, out);
}

// Round 6
// 2381.198 us; speedup vs baseline: 1792.6746x; 1792.6746x over previous
//
#include <hip/hip_runtime.h>
#include <hip/hip_fp16.h>

#define H_ 1024
#define B_ 256
#define T_ 256
#define C_ 10

typedef _Float16 f16x8 __attribute__((ext_vector_type(8)));
typedef float f32x4 __attribute__((ext_vector_type(4)));

__device__ __forceinline__ float sigm_f(float v) { return 1.f / (1.f + __expf(-v)); }
__device__ __forceinline__ float tanh_f(float v) {
  v = fminf(fmaxf(v, -15.f), 15.f);
  float e = __expf(2.f * v);
  return (e - 1.f) / (e + 1.f);
}

// agent-scope (coherence-point) 16B load as two 8B relaxed atomic loads.
// Proven correct for cross-WG h exchange (r1/r2). sc0/L2 games are dead
// (R3 hang, R4 absmax, R5 poll-grind): L1-bypass exists only at agent scope.
__device__ __forceinline__ f16x8 load_h8_agent(const _Float16* p) {
  const unsigned long long* q = reinterpret_cast<const unsigned long long*>(p);
  unsigned long long lo = __hip_atomic_load(q,     __ATOMIC_RELAXED, __HIP_MEMORY_SCOPE_AGENT);
  unsigned long long hi = __hip_atomic_load(q + 1, __ATOMIC_RELAXED, __HIP_MEMORY_SCOPE_AGENT);
  union { unsigned long long u[2]; f16x8 v; } r;
  r.u[0] = lo; r.u[1] = hi;
  return r.v;
}

// Persistent LSTM. Grid: 256 WGs = 32 row-groups (r) x 8 col-groups (g).
// Each WG: 32 hidden units x 32 batch cols, all 4 gates. 8 waves = 2 M-groups
// x 4 K-slices; weights (M=64 x K=256 fp16 per wave) stationary in 128 VGPRs.
// Row permutation m = 4*u + gate so a lane's f32x4 accumulator holds the 4
// gate preactivations of one (unit, col).
// Sync: per-producer flags, agent scope. Wave kg polls exactly its 8
// producers. KEY r6 change: all 16 B-fragment loads are issued into registers
// BEFORE the MFMA block -> one fabric round-trip per step instead of eight.
__global__ __launch_bounds__(512, 2) void lstm_main(
    const float* __restrict__ x,
    const float* __restrict__ Wgh, const float* __restrict__ Wih,
    const float* __restrict__ Wfh, const float* __restrict__ Woh,
    const float* __restrict__ Wgx, const float* __restrict__ Wix,
    const float* __restrict__ Wfx, const float* __restrict__ Wox,
    const float* __restrict__ bg, const float* __restrict__ bi,
    const float* __restrict__ bf, const float* __restrict__ bo,
    _Float16* __restrict__ hT, unsigned int* __restrict__ flags)
{
  const int bid  = blockIdx.x;
  const int g    = bid & 7;      // col group
  const int r    = bid >> 3;     // row group 0..31
  const int tid  = threadIdx.x;
  const int wid  = tid >> 6;     // wave 0..7
  const int lane = tid & 63;
  const int mg   = wid >> 2;     // M-group 0..1
  const int kg   = wid & 3;      // K-slice 0..3
  const int q    = lane >> 4;    // 0..3
  const int rlo  = lane & 15;
  const int c0   = g * 32;       // batch col base

  __shared__ float part[32 * 4 * 128];  // [c_local][kg][m] f32, XOR-swizzled

  // ---- A fragments: stationary weights in registers -----------------------
  f16x8 A[32];
  {
    const int gate = rlo & 3;
    const float* Wsel = (gate == 0) ? Wgh : (gate == 1) ? Wih : (gate == 2) ? Wfh : Woh;
    #pragma unroll
    for (int f = 0; f < 32; ++f) {
      const int mt  = f >> 3, kkl = f & 7;
      const int u   = mg * 16 + mt * 4 + (rlo >> 2);
      const int k   = kg * 256 + kkl * 32 + q * 8;
      const float4* p = reinterpret_cast<const float4*>(
          Wsel + (size_t)(r * 32 + u) * H_ + k);
      float4 lo = p[0], hi = p[1];
      f16x8 a;
      a[0]=(_Float16)lo.x; a[1]=(_Float16)lo.y; a[2]=(_Float16)lo.z; a[3]=(_Float16)lo.w;
      a[4]=(_Float16)hi.x; a[5]=(_Float16)hi.y; a[6]=(_Float16)hi.z; a[7]=(_Float16)hi.w;
      A[f] = a;
    }
  }

  // ---- per-thread elementwise constants -----------------------------------
  const int c_l = tid >> 4;
  const int uu  = tid & 15;
  float wx0[4], wx1[4], bb0[4], bb1[4];
  {
    const int u0 = r * 32 + uu, u1 = u0 + 16;
    wx0[0]=Wgx[u0]; wx0[1]=Wix[u0]; wx0[2]=Wfx[u0]; wx0[3]=Wox[u0];
    wx1[0]=Wgx[u1]; wx1[1]=Wix[u1]; wx1[2]=Wfx[u1]; wx1[3]=Wox[u1];
    bb0[0]=bg[u0];  bb0[1]=bi[u0];  bb0[2]=bf[u0];  bb0[3]=bo[u0];
    bb1[0]=bg[u1];  bb1[1]=bi[u1];  bb1[2]=bf[u1];  bb1[3]=bo[u1];
  }
  float cs0 = 0.f, cs1 = 0.f;
  const float* xrow = x + (size_t)(c0 + c_l) * T_;

  unsigned int* myflags = flags + ((size_t)(g * 32 + kg * 8 + (lane & 7)) * 16);
  unsigned int* ownflag = flags + ((size_t)(g * 32 + r) * 16);

  for (int t = 0; t < T_; ++t) {
    // ---- per-wave wait: only the 8 producers feeding this K-slice ----
    if (t > 0) {
      const unsigned tgt = (unsigned)t;
      int guard = 0;
      for (;;) {
        unsigned v = tgt;
        if (lane < 8)
          v = __hip_atomic_load(myflags, __ATOMIC_RELAXED, __HIP_MEMORY_SCOPE_AGENT);
        if (__all((int)(v >= tgt))) break;
        if (++guard > (1 << 20)) break;  // bailout: fails absmax, never hangs
        __builtin_amdgcn_s_sleep(1);
      }
      asm volatile("" ::: "memory");
    }

    // ---- batched B-fragment loads: ONE fabric round trip for all 16 ----
    const _Float16* hbuf = hT + (size_t)(t & 1) * (B_ * H_);
    const _Float16* hb0 = hbuf + (size_t)(c0 + rlo) * H_ + kg * 256 + q * 8;
    const _Float16* hb1 = hb0 + 16 * (size_t)H_;

    f16x8 B0[8], B1[8];
    #pragma unroll
    for (int kkl = 0; kkl < 8; ++kkl) {
      B0[kkl] = load_h8_agent(hb0 + kkl * 32);
      B1[kkl] = load_h8_agent(hb1 + kkl * 32);
    }

    // ---- GEMM: preactivations for this WG's 128(M) x 32(N) tile ----
    f32x4 acc[4][2];
    #pragma unroll
    for (int mt = 0; mt < 4; ++mt) {
      acc[mt][0] = (f32x4){0.f, 0.f, 0.f, 0.f};
      acc[mt][1] = (f32x4){0.f, 0.f, 0.f, 0.f};
    }
    #pragma unroll
    for (int kkl = 0; kkl < 8; ++kkl) {
      #pragma unroll
      for (int mt = 0; mt < 4; ++mt) {
        acc[mt][0] = __builtin_amdgcn_mfma_f32_16x16x32_f16(A[mt*8+kkl], B0[kkl], acc[mt][0], 0, 0, 0);
        acc[mt][1] = __builtin_amdgcn_mfma_f32_16x16x32_f16(A[mt*8+kkl], B1[kkl], acc[mt][1], 0, 0, 0);
      }
    }

    // ---- K-partials to LDS (C/D layout: col=lane&15, row=(lane>>4)*4+reg) ----
    #pragma unroll
    for (int mt = 0; mt < 4; ++mt) {
      #pragma unroll
      for (int nt = 0; nt < 2; ++nt) {
        const int c_loc = nt * 16 + rlo;
        const int m = mg * 64 + mt * 16 + 4 * q;
        unsigned addr = (unsigned)(c_loc * 2048 + kg * 512 + m * 4);
        addr ^= (unsigned)((c_loc & 7) << 4);
        *reinterpret_cast<f32x4*>(reinterpret_cast<char*>(part) + addr) = acc[mt][nt];
      }
    }
    __syncthreads();

    // ---- reduce over kg + gate nonlinearities + state update ----
    const float xv = xrow[t];
    unsigned short hbits0, hbits1;
    {
      unsigned lin = (unsigned)(c_l * 2048 + uu * 16);
      f32x4 s = *reinterpret_cast<const f32x4*>(
          reinterpret_cast<const char*>(part) + (lin ^ ((unsigned)(c_l & 7) << 4)));
      #pragma unroll
      for (int kgi = 1; kgi < 4; ++kgi) {
        unsigned l2 = lin + (unsigned)(kgi * 512);
        s += *reinterpret_cast<const f32x4*>(
            reinterpret_cast<const char*>(part) + (l2 ^ ((unsigned)(c_l & 7) << 4)));
      }
      float pg = s[0] + wx0[0]*xv + bb0[0];
      float pi = s[1] + wx0[1]*xv + bb0[1];
      float pf = s[2] + wx0[2]*xv + bb0[2];
      float po = s[3] + wx0[3]*xv + bb0[3];
      float gg = tanh_f(pg), ii = sigm_f(pi), ff = sigm_f(pf), oo = sigm_f(po);
      cs0 = gg * ii + cs0 * ff;
      hbits0 = __builtin_bit_cast(unsigned short, (_Float16)(tanh_f(cs0) * oo));
    }
    {
      unsigned lin = (unsigned)(c_l * 2048 + (uu + 16) * 16);
      f32x4 s = *reinterpret_cast<const f32x4*>(
          reinterpret_cast<const char*>(part) + (lin ^ ((unsigned)(c_l & 7) << 4)));
      #pragma unroll
      for (int kgi = 1; kgi < 4; ++kgi) {
        unsigned l2 = lin + (unsigned)(kgi * 512);
        s += *reinterpret_cast<const f32x4*>(
            reinterpret_cast<const char*>(part) + (l2 ^ ((unsigned)(c_l & 7) << 4)));
      }
      float pg = s[0] + wx1[0]*xv + bb1[0];
      float pi = s[1] + wx1[1]*xv + bb1[1];
      float pf = s[2] + wx1[2]*xv + bb1[2];
      float po = s[3] + wx1[3]*xv + bb1[3];
      float gg = tanh_f(pg), ii = sigm_f(pi), ff = sigm_f(pf), oo = sigm_f(po);
      cs1 = gg * ii + cs1 * ff;
      hbits1 = __builtin_bit_cast(unsigned short, (_Float16)(tanh_f(cs1) * oo));
    }

    // ---- store h(t+1) to the other parity buffer (agent-coherent) ----
    {
      _Float16* hout = hT + (size_t)((t + 1) & 1) * (B_ * H_)
                          + (size_t)(c0 + c_l) * H_ + r * 32;
      int nb0 = __shfl_down((int)hbits0, 1);
      int nb1 = __shfl_down((int)hbits1, 1);
      if ((uu & 1) == 0) {
        unsigned v0 = (unsigned)hbits0 | ((unsigned)(unsigned short)nb0 << 16);
        unsigned v1 = (unsigned)hbits1 | ((unsigned)(unsigned short)nb1 << 16);
        __hip_atomic_store(reinterpret_cast<unsigned int*>(hout + uu), v0,
                           __ATOMIC_RELAXED, __HIP_MEMORY_SCOPE_AGENT);
        __hip_atomic_store(reinterpret_cast<unsigned int*>(hout + uu + 16), v1,
                           __ATOMIC_RELAXED, __HIP_MEMORY_SCOPE_AGENT);
      }
    }
    // explicit per-thread drain + barrier: every h store is fabric-acked
    // before any thread publishes the flag below
    asm volatile("s_waitcnt vmcnt(0)" ::: "memory");
    __syncthreads();
    if (tid == 0)
      __hip_atomic_store(ownflag, (unsigned)(t + 1),
                         __ATOMIC_RELAXED, __HIP_MEMORY_SCOPE_AGENT);
  }
}

// out[b][cls] = sum_u W_ph[cls][u] * h_final[u][b] + b_p[cls]
__global__ void lstm_proj(const _Float16* __restrict__ hT,
                          const float* __restrict__ Wph,
                          const float* __restrict__ bp,
                          float* __restrict__ out)
{
  const int b = blockIdx.x;
  const int l = threadIdx.x;
  const _Float16* hrow = hT + (size_t)b * H_;  // T even -> final h in parity-0
  float p[C_];
  #pragma unroll
  for (int cls = 0; cls < C_; ++cls) p[cls] = 0.f;
  for (int u = l; u < H_; u += 64) {
    float hv = (float)hrow[u];
    #pragma unroll
    for (int cls = 0; cls < C_; ++cls) p[cls] += hv * Wph[cls * H_ + u];
  }
  #pragma unroll
  for (int cls = 0; cls < C_; ++cls) {
    float v = p[cls];
    #pragma unroll
    for (int off = 32; off > 0; off >>= 1) v += __shfl_down(v, off);
    if (l == 0) out[b * C_ + cls] = v + bp[cls];
  }
}

extern "C" void kernel_launch(void* const* d_in, const int* in_sizes, int n_in,
                              void* d_out, int out_size, void* d_ws, size_t ws_size,
                              hipStream_t stream) {
  const float* x   = (const float*)d_in[0];
  const float* Wgx = (const float*)d_in[1];
  const float* Wgh = (const float*)d_in[2];
  const float* Wix = (const float*)d_in[3];
  const float* Wih = (const float*)d_in[4];
  const float* Wfx = (const float*)d_in[5];
  const float* Wfh = (const float*)d_in[6];
  const float* Wox = (const float*)d_in[7];
  const float* Woh = (const float*)d_in[8];
  const float* Wph = (const float*)d_in[9];
  const float* bg  = (const float*)d_in[10];
  const float* bi  = (const float*)d_in[11];
  const float* bf  = (const float*)d_in[12];
  const float* bo  = (const float*)d_in[13];
  const float* bp  = (const float*)d_in[14];
  float* out = (float*)d_out;

  // ws layout: [0,1MB) hT fp16 double buffer [2][B][H];
  //            [1MB, 1MB+16KB) per-producer flags (256 x 64B)
  _Float16* hT = (_Float16*)d_ws;
  const size_t hT_bytes = (size_t)2 * B_ * H_ * sizeof(_Float16);  // 1 MiB
  unsigned int* flags = (unsigned int*)((char*)d_ws + hT_bytes);

  hipMemsetAsync(d_ws, 0, hT_bytes + 16384, stream);  // h(0)=0, flags=0

  lstm_main<<<256, 512, 0, stream>>>(x, Wgh, Wih, Wfh, Woh,
                                     Wgx, Wix, Wfx, Wox,
                                     bg, bi, bf, bo, hT, flags);
  lstm_proj<<<256, 64, 0, stream>>>(hT, Wph, bp, out);
}

// Round 7
// 1711.609 us; speedup vs baseline: 2493.9775x; 1.3912x over previous
//
#include <hip/hip_runtime.h>
#include <hip/hip_fp16.h>

#define H_ 1024
#define B_ 256
#define T_ 256
#define C_ 10

typedef _Float16 f16x8 __attribute__((ext_vector_type(8)));
typedef float f32x4 __attribute__((ext_vector_type(4)));

__device__ __forceinline__ float sigm_f(float v) { return 1.f / (1.f + __expf(-v)); }
__device__ __forceinline__ float tanh_f(float v) {
  v = fminf(fmaxf(v, -15.f), 15.f);
  float e = __expf(2.f * v);
  return (e - 1.f) / (e + 1.f);
}

// cross-XCD-safe coherence-point load (bypasses L1+L2) — slow-path h reads
__device__ __forceinline__ f16x8 load_h8_agent(const _Float16* p) {
  const unsigned long long* q = reinterpret_cast<const unsigned long long*>(p);
  unsigned long long lo = __hip_atomic_load(q,     __ATOMIC_RELAXED, __HIP_MEMORY_SCOPE_AGENT);
  unsigned long long hi = __hip_atomic_load(q + 1, __ATOMIC_RELAXED, __HIP_MEMORY_SCOPE_AGENT);
  union { unsigned long long u[2]; f16x8 v; } r;
  r.u[0] = lo; r.u[1] = hi;
  return r.v;
}

// zero flags/scal/h0 with agent-scope stores (write-through to IC: no dirty
// L2 lines anywhere -> no eviction races with the poison fill or past replays)
__global__ void lstm_init(unsigned* __restrict__ flags, int flagDw,
                          unsigned* __restrict__ scal,
                          unsigned* __restrict__ h0u, int h0Dw) {
  int i = blockIdx.x * blockDim.x + threadIdx.x;
  int n = gridDim.x * blockDim.x;
  for (int k = i; k < flagDw; k += n)
    __hip_atomic_store(flags + k, 0u, __ATOMIC_RELAXED, __HIP_MEMORY_SCOPE_AGENT);
  for (int k = i; k < 1024; k += n)
    __hip_atomic_store(scal + k, 0u, __ATOMIC_RELAXED, __HIP_MEMORY_SCOPE_AGENT);
  for (int k = i; k < h0Dw; k += n)
    __hip_atomic_store(h0u + k, 0u, __ATOMIC_RELAXED, __HIP_MEMORY_SCOPE_AGENT);
}

// Persistent LSTM. 256 WGs = 32 row-groups (r) x 8 col-groups (g); each WG:
// 32 hidden units x 32 batch cols, all 4 gates; weights stationary in VGPRs
// (row permutation m = 4*u + gate). Col-groups are communication-CLOSED: only
// the 32 WGs of a group exchange h -> same-XCD (runtime-voted via XCC_ID).
// rot=1 FAST: h rotates through T+1 fresh buffers; producers use plain
//   write-through stores (land in shared XCD L2, ~fast ack); consumers use
//   plain cached loads (fresh addresses -> no staleness possible). Flags are
//   ALWAYS sc1/agent (proven visible) -> no hang path ever.
// rot=1 SLOW (vote failed) or rot=0: exact r6 agent-scope semantics.
// All modes execute identical FP ops in identical order -> identical bits.
__global__ __launch_bounds__(512, 2) void lstm_main(
    const float* __restrict__ x,
    const float* __restrict__ Wgh, const float* __restrict__ Wih,
    const float* __restrict__ Wfh, const float* __restrict__ Woh,
    const float* __restrict__ Wgx, const float* __restrict__ Wix,
    const float* __restrict__ Wfx, const float* __restrict__ Wox,
    const float* __restrict__ bg, const float* __restrict__ bi,
    const float* __restrict__ bf, const float* __restrict__ bo,
    _Float16* __restrict__ hT, unsigned int* __restrict__ flags,
    unsigned int* __restrict__ scal, int rot)
{
  const int bid  = blockIdx.x;
  const int g    = bid & 7;      // col group (one XCD, verified by vote)
  const int r    = bid >> 3;     // row group 0..31
  const int tid  = threadIdx.x;
  const int wid  = tid >> 6;     // wave 0..7
  const int lane = tid & 63;
  const int mg   = wid >> 2;     // M-group 0..1
  const int kg   = wid & 3;      // K-slice 0..3
  const int q    = lane >> 4;    // 0..3
  const int rlo  = lane & 15;
  const int c0   = g * 32;       // batch col base
  const size_t HB = (size_t)B_ * H_;

  __shared__ float part[32 * 4 * 128];  // [c_local][kg][m] f32, XOR-swizzled
  __shared__ unsigned mode_sh;

  // ---- per-col-group XCD co-location vote (machinery proven r3-r5) --------
  {
    unsigned xcc;
    asm volatile("s_getreg_b32 %0, hwreg(HW_REG_XCC_ID)" : "=s"(xcc));
    if (tid == 0) {
      unsigned* mask  = scal + g;
      unsigned* ready = scal + 8 + g;
      __hip_atomic_fetch_or(mask, 1u << (xcc & 31),
                            __ATOMIC_RELAXED, __HIP_MEMORY_SCOPE_AGENT);
      __hip_atomic_fetch_add(ready, 1u, __ATOMIC_RELEASE, __HIP_MEMORY_SCOPE_AGENT);
      int gd = 0; bool trip = false;
      while (__hip_atomic_load(ready, __ATOMIC_RELAXED, __HIP_MEMORY_SCOPE_AGENT) < 32u) {
        if (++gd > (1 << 22)) { trip = true; break; }
        __builtin_amdgcn_s_sleep(8);
      }
      unsigned m = __hip_atomic_load(mask, __ATOMIC_ACQUIRE, __HIP_MEMORY_SCOPE_AGENT);
      mode_sh = (rot && !trip && __popc((int)m) == 1) ? 1u : 2u;
    }
    __syncthreads();
  }
  const bool fast = (mode_sh == 1u);

  // ---- A fragments: stationary weights in registers -----------------------
  f16x8 A[32];
  {
    const int gate = rlo & 3;
    const float* Wsel = (gate == 0) ? Wgh : (gate == 1) ? Wih : (gate == 2) ? Wfh : Woh;
    #pragma unroll
    for (int f = 0; f < 32; ++f) {
      const int mt  = f >> 3, kkl = f & 7;
      const int u   = mg * 16 + mt * 4 + (rlo >> 2);
      const int k   = kg * 256 + kkl * 32 + q * 8;
      const float4* p = reinterpret_cast<const float4*>(
          Wsel + (size_t)(r * 32 + u) * H_ + k);
      float4 lo = p[0], hi = p[1];
      f16x8 a;
      a[0]=(_Float16)lo.x; a[1]=(_Float16)lo.y; a[2]=(_Float16)lo.z; a[3]=(_Float16)lo.w;
      a[4]=(_Float16)hi.x; a[5]=(_Float16)hi.y; a[6]=(_Float16)hi.z; a[7]=(_Float16)hi.w;
      A[f] = a;
    }
  }

  // ---- per-thread elementwise constants -----------------------------------
  const int c_l = tid >> 4;
  const int uu  = tid & 15;
  float wx0[4], wx1[4], bb0[4], bb1[4];
  {
    const int u0 = r * 32 + uu, u1 = u0 + 16;
    wx0[0]=Wgx[u0]; wx0[1]=Wix[u0]; wx0[2]=Wfx[u0]; wx0[3]=Wox[u0];
    wx1[0]=Wgx[u1]; wx1[1]=Wix[u1]; wx1[2]=Wfx[u1]; wx1[3]=Wox[u1];
    bb0[0]=bg[u0];  bb0[1]=bi[u0];  bb0[2]=bf[u0];  bb0[3]=bo[u0];
    bb1[0]=bg[u1];  bb1[1]=bi[u1];  bb1[2]=bf[u1];  bb1[3]=bo[u1];
  }
  float cs0 = 0.f, cs1 = 0.f;
  const float* xrow = x + (size_t)(c0 + c_l) * T_;

  const int flagIdxPoll = (g * 32 + kg * 8 + (lane & 7)) * 16;
  const int flagIdxOwn  = (g * 32 + r) * 16;

  for (int t = 0; t < T_; ++t) {
    // ---- rotated (fresh-address) or r6 (parity) buffers -------------------
    const _Float16* hbr = hT + (size_t)(rot ? t : (t & 1)) * HB;
    _Float16*       hbw = hT + (size_t)(rot ? (t + 1) : ((t + 1) & 1)) * HB;
    unsigned* pub  = (rot ? flags + (size_t)t * 4096 : flags) + flagIdxOwn;

    // ---- per-wave wait: only the 8 producers feeding this K-slice ----
    if (t > 0) {
      unsigned* myf = (rot ? flags + (size_t)(t - 1) * 4096 : flags) + flagIdxPoll;
      const unsigned tgt = rot ? 1u : (unsigned)t;
      int guard = 0;
      for (;;) {
        unsigned v = tgt;
        if (lane < 8)
          v = __hip_atomic_load(myf, __ATOMIC_RELAXED, __HIP_MEMORY_SCOPE_AGENT);
        if (__all((int)(v >= tgt))) break;
        if (++guard > (1 << 19)) break;  // flags are sc1-proven: never trips
        __builtin_amdgcn_s_sleep(1);
      }
      asm volatile("" ::: "memory");
    }

    // ---- B-fragment loads: L2-cached (fast) or IC (slow) ----
    const _Float16* hb0 = hbr + (size_t)(c0 + rlo) * H_ + kg * 256 + q * 8;
    const _Float16* hb1 = hb0 + 16 * (size_t)H_;

    f16x8 B0[8], B1[8];
    if (fast) {
      #pragma unroll
      for (int kkl = 0; kkl < 8; ++kkl) {
        B0[kkl] = *reinterpret_cast<const f16x8*>(hb0 + kkl * 32);
        B1[kkl] = *reinterpret_cast<const f16x8*>(hb1 + kkl * 32);
      }
    } else {
      #pragma unroll
      for (int kkl = 0; kkl < 8; ++kkl) {
        B0[kkl] = load_h8_agent(hb0 + kkl * 32);
        B1[kkl] = load_h8_agent(hb1 + kkl * 32);
      }
    }

    // ---- GEMM: preactivations for this WG's 128(M) x 32(N) tile ----
    f32x4 acc[4][2];
    #pragma unroll
    for (int mt = 0; mt < 4; ++mt) {
      acc[mt][0] = (f32x4){0.f, 0.f, 0.f, 0.f};
      acc[mt][1] = (f32x4){0.f, 0.f, 0.f, 0.f};
    }
    #pragma unroll
    for (int kkl = 0; kkl < 8; ++kkl) {
      #pragma unroll
      for (int mt = 0; mt < 4; ++mt) {
        acc[mt][0] = __builtin_amdgcn_mfma_f32_16x16x32_f16(A[mt*8+kkl], B0[kkl], acc[mt][0], 0, 0, 0);
        acc[mt][1] = __builtin_amdgcn_mfma_f32_16x16x32_f16(A[mt*8+kkl], B1[kkl], acc[mt][1], 0, 0, 0);
      }
    }

    // ---- K-partials to LDS (C/D layout: col=lane&15, row=(lane>>4)*4+reg) ----
    #pragma unroll
    for (int mt = 0; mt < 4; ++mt) {
      #pragma unroll
      for (int nt = 0; nt < 2; ++nt) {
        const int c_loc = nt * 16 + rlo;
        const int m = mg * 64 + mt * 16 + 4 * q;
        unsigned addr = (unsigned)(c_loc * 2048 + kg * 512 + m * 4);
        addr ^= (unsigned)((c_loc & 7) << 4);
        *reinterpret_cast<f32x4*>(reinterpret_cast<char*>(part) + addr) = acc[mt][nt];
      }
    }
    __syncthreads();

    // ---- reduce over kg + gate nonlinearities + state update ----
    const float xv = xrow[t];
    unsigned short hbits0, hbits1;
    {
      unsigned lin = (unsigned)(c_l * 2048 + uu * 16);
      f32x4 s = *reinterpret_cast<const f32x4*>(
          reinterpret_cast<const char*>(part) + (lin ^ ((unsigned)(c_l & 7) << 4)));
      #pragma unroll
      for (int kgi = 1; kgi < 4; ++kgi) {
        unsigned l2 = lin + (unsigned)(kgi * 512);
        s += *reinterpret_cast<const f32x4*>(
            reinterpret_cast<const char*>(part) + (l2 ^ ((unsigned)(c_l & 7) << 4)));
      }
      float pg = s[0] + wx0[0]*xv + bb0[0];
      float pi = s[1] + wx0[1]*xv + bb0[1];
      float pf = s[2] + wx0[2]*xv + bb0[2];
      float po = s[3] + wx0[3]*xv + bb0[3];
      float gg = tanh_f(pg), ii = sigm_f(pi), ff = sigm_f(pf), oo = sigm_f(po);
      cs0 = gg * ii + cs0 * ff;
      hbits0 = __builtin_bit_cast(unsigned short, (_Float16)(tanh_f(cs0) * oo));
    }
    {
      unsigned lin = (unsigned)(c_l * 2048 + (uu + 16) * 16);
      f32x4 s = *reinterpret_cast<const f32x4*>(
          reinterpret_cast<const char*>(part) + (lin ^ ((unsigned)(c_l & 7) << 4)));
      #pragma unroll
      for (int kgi = 1; kgi < 4; ++kgi) {
        unsigned l2 = lin + (unsigned)(kgi * 512);
        s += *reinterpret_cast<const f32x4*>(
            reinterpret_cast<const char*>(part) + (l2 ^ ((unsigned)(c_l & 7) << 4)));
      }
      float pg = s[0] + wx1[0]*xv + bb1[0];
      float pi = s[1] + wx1[1]*xv + bb1[1];
      float pf = s[2] + wx1[2]*xv + bb1[2];
      float po = s[3] + wx1[3]*xv + bb1[3];
      float gg = tanh_f(pg), ii = sigm_f(pi), ff = sigm_f(pf), oo = sigm_f(po);
      cs1 = gg * ii + cs1 * ff;
      hbits1 = __builtin_bit_cast(unsigned short, (_Float16)(tanh_f(cs1) * oo));
    }

    // ---- store h(t+1) ----
    {
      _Float16* hout = hbw + (size_t)(c0 + c_l) * H_ + r * 32;
      int nb0 = __shfl_down((int)hbits0, 1);
      int nb1 = __shfl_down((int)hbits1, 1);
      if ((uu & 1) == 0) {
        unsigned v0 = (unsigned)hbits0 | ((unsigned)(unsigned short)nb0 << 16);
        unsigned v1 = (unsigned)hbits1 | ((unsigned)(unsigned short)nb1 << 16);
        unsigned int* p0 = reinterpret_cast<unsigned int*>(hout + uu);
        unsigned int* p1 = reinterpret_cast<unsigned int*>(hout + uu + 16);
        if (fast && t != T_ - 1) {
          // write-through L1 -> shared XCD L2 (fresh addresses: consumers'
          // caches cannot hold stale copies). Final step goes agent-scope so
          // lstm_proj (arbitrary XCDs) sees it at the coherence point.
          *(volatile unsigned int*)p0 = v0;
          *(volatile unsigned int*)p1 = v1;
        } else {
          __hip_atomic_store(p0, v0, __ATOMIC_RELAXED, __HIP_MEMORY_SCOPE_AGENT);
          __hip_atomic_store(p1, v1, __ATOMIC_RELAXED, __HIP_MEMORY_SCOPE_AGENT);
        }
      }
    }
    // drain: fast-mode acks come from the XCD L2 (cheap); then barrier, flag
    asm volatile("s_waitcnt vmcnt(0)" ::: "memory");
    __syncthreads();
    if (tid == 0)
      __hip_atomic_store(pub, rot ? 1u : (unsigned)(t + 1),
                         __ATOMIC_RELAXED, __HIP_MEMORY_SCOPE_AGENT);
  }
}

// out[b][cls] = sum_u W_ph[cls][u] * h_final[u][b] + b_p[cls]
__global__ void lstm_proj(const _Float16* __restrict__ hfin,
                          const float* __restrict__ Wph,
                          const float* __restrict__ bp,
                          float* __restrict__ out)
{
  const int b = blockIdx.x;
  const int l = threadIdx.x;
  const _Float16* hrow = hfin + (size_t)b * H_;
  float p[C_];
  #pragma unroll
  for (int cls = 0; cls < C_; ++cls) p[cls] = 0.f;
  for (int u = l; u < H_; u += 64) {
    float hv = (float)hrow[u];
    #pragma unroll
    for (int cls = 0; cls < C_; ++cls) p[cls] += hv * Wph[cls * H_ + u];
  }
  #pragma unroll
  for (int cls = 0; cls < C_; ++cls) {
    float v = p[cls];
    #pragma unroll
    for (int off = 32; off > 0; off >>= 1) v += __shfl_down(v, off);
    if (l == 0) out[b * C_ + cls] = v + bp[cls];
  }
}

extern "C" void kernel_launch(void* const* d_in, const int* in_sizes, int n_in,
                              void* d_out, int out_size, void* d_ws, size_t ws_size,
                              hipStream_t stream) {
  const float* x   = (const float*)d_in[0];
  const float* Wgx = (const float*)d_in[1];
  const float* Wgh = (const float*)d_in[2];
  const float* Wix = (const float*)d_in[3];
  const float* Wih = (const float*)d_in[4];
  const float* Wfx = (const float*)d_in[5];
  const float* Wfh = (const float*)d_in[6];
  const float* Wox = (const float*)d_in[7];
  const float* Woh = (const float*)d_in[8];
  const float* Wph = (const float*)d_in[9];
  const float* bg  = (const float*)d_in[10];
  const float* bi  = (const float*)d_in[11];
  const float* bf  = (const float*)d_in[12];
  const float* bo  = (const float*)d_in[13];
  const float* bp  = (const float*)d_in[14];
  float* out = (float*)d_out;

  const size_t HB = (size_t)B_ * H_;                     // elems per h buffer
  // rot layout (low addresses only — the poison fill's dirty-L2 tail lives at
  // the TOP of the 256MiB ws): [0,4MB) flag rotation (T x 16KB);
  // [4MB,+4KB) vote scalars; [8MB, 8MB+257*512KB) h rotation.
  const size_t need = (8u << 20) + (size_t)(T_ + 1) * HB * sizeof(_Float16);
  const int rot = (ws_size >= need) ? 1 : 0;

  unsigned *flags, *scal; _Float16 *hT; int flagDw;
  if (rot) {
    flags  = (unsigned*)d_ws;                            // 4 MB
    scal   = (unsigned*)((char*)d_ws + (4u << 20));      // 4 KB
    hT     = (_Float16*)((char*)d_ws + (8u << 20));      // 257 buffers
    flagDw = T_ * 4096;
  } else {
    hT     = (_Float16*)d_ws;                            // 2 buffers (1 MB)
    flags  = (unsigned*)((char*)d_ws + 2 * HB * sizeof(_Float16));
    scal   = flags + 4096;
    flagDw = 4096;
  }

  lstm_init<<<256, 256, 0, stream>>>(flags, flagDw, scal,
                                     (unsigned*)hT, (int)(HB / 2));
  lstm_main<<<256, 512, 0, stream>>>(x, Wgh, Wih, Wfh, Woh,
                                     Wgx, Wix, Wfx, Wox,
                                     bg, bi, bf, bo, hT, flags, scal, rot);
  lstm_proj<<<256, 64, 0, stream>>>(hT + (size_t)(rot ? T_ : 0) * HB,
                                    Wph, bp, out);
}